// Round 1
// 845.327 us; speedup vs baseline: 1.0198x; 1.0198x over previous
//
#include <hip/hip_runtime.h>
#include <stdint.h>
#include <stddef.h>

#define TOKS 4096
#define DH   2048
#define DI   8192

typedef __attribute__((ext_vector_type(8))) short short8v;
typedef __attribute__((ext_vector_type(4))) short short4v;
typedef __attribute__((ext_vector_type(4))) float floatx4;

__device__ __forceinline__ float b2f(short s) {
  union { unsigned u; float f; } v;
  v.u = ((unsigned)(unsigned short)s) << 16;
  return v.f;
}
__device__ __forceinline__ short f2b(float f) {
  union { float f; unsigned u; } v; v.f = f;
  unsigned r = (v.u + 0x7fffu + ((v.u >> 16) & 1u)) >> 16;  // RNE
  return (short)(unsigned short)r;
}
__device__ __forceinline__ void gload_lds16(const void* g, void* l) {
  __builtin_amdgcn_global_load_lds((const __attribute__((address_space(1))) void*)g,
                                   (__attribute__((address_space(3))) void*)l, 16, 0, 0);
}

// ---------------- fp32 -> bf16 elementwise (x) ----------------
__global__ __launch_bounds__(256) void cvt_f32_to_bf16(const float* __restrict__ in,
                                                       short* __restrict__ out) {
  size_t i = (size_t)blockIdx.x * 256 + threadIdx.x;
  floatx4 v = *(const floatx4*)&in[i * 4];
  short4v o;
  o[0] = f2b(v[0]); o[1] = f2b(v[1]); o[2] = f2b(v[2]); o[3] = f2b(v[3]);
  *(short4v*)&out[i * 4] = o;
}

// ---------- fp32 [K][N] -> bf16 [N][K] transpose (strided/interleaved out) ----
__global__ __launch_bounds__(256) void transpose_to_bf16(const float* __restrict__ in,
                                                         short* __restrict__ out,
                                                         int K, int N,
                                                         int rstride, int roff) {
  __shared__ float tile[32][33];
  const int n0 = blockIdx.x * 32, k0 = blockIdx.y * 32;
  const int tx = threadIdx.x & 31, ty = threadIdx.x >> 5;  // ty: 0..7
#pragma unroll
  for (int yy = 0; yy < 32; yy += 8)
    tile[ty + yy][tx] = in[(size_t)(k0 + ty + yy) * N + n0 + tx];
  __syncthreads();
#pragma unroll
  for (int yy = 0; yy < 32; yy += 8)
    out[((size_t)(n0 + ty + yy) * rstride + roff) * K + k0 + tx] = f2b(tile[tx][ty + yy]);
}

// ---------------- router + const-expert gates (fp32 exact) ----------------
#define RT_TPB 8
__global__ __launch_bounds__(256) void router_kernel(const float* __restrict__ x,
                                                     const float* __restrict__ gw1,
                                                     const float* __restrict__ gw2,
                                                     const float* __restrict__ cwg,
                                                     float* __restrict__ logits_out,
                                                     float* __restrict__ coef) {
  const int wave = threadIdx.x >> 6, lane = threadIdx.x & 63;
  const int tok0 = blockIdx.x * RT_TPB;
  __shared__ float xs[RT_TPB][512];   // 16 KB chunk
  __shared__ float ll[RT_TPB][8];
  __shared__ float cd[RT_TPB][4];

  float tj[2] = {0.f, 0.f};           // gate-hidden partial, col = lane
  float cda[2][4] = {{0.f,0.f,0.f,0.f},{0.f,0.f,0.f,0.f}};  // const-dot partials

  const int st = threadIdx.x >> 5;        // staging token 0..7
  const int sl = threadIdx.x & 31;

  for (int c = 0; c < 4; ++c) {
    const int dbase = c * 512;
#pragma unroll
    for (int r = 0; r < 4; ++r) {
      const int idx = r * 128 + sl * 4;
      *(floatx4*)&xs[st][idx] = *(const floatx4*)&x[(size_t)(tok0 + st) * DH + dbase + idx];
    }
    __syncthreads();
    for (int d = 0; d < 512; ++d) {
      const float g = gw1[(size_t)(dbase + d) * 64 + lane];
      tj[0] += xs[wave * 2 + 0][d] * g;
      tj[1] += xs[wave * 2 + 1][d] * g;
    }
#pragma unroll
    for (int dq = 0; dq < 8; ++dq) {
      const int d = dq * 64 + lane;
      const float w0 = cwg[(size_t)(dbase + d) * 2 + 0];
      const float w1 = cwg[(size_t)(dbase + d) * 2 + 1];
      const float w2 = cwg[(size_t)DH * 2 + (dbase + d) * 2 + 0];
      const float w3 = cwg[(size_t)DH * 2 + (dbase + d) * 2 + 1];
#pragma unroll
      for (int t = 0; t < 2; ++t) {
        const float xv = xs[wave * 2 + t][d];
        cda[t][0] += xv * w0; cda[t][1] += xv * w1;
        cda[t][2] += xv * w2; cda[t][3] += xv * w3;
      }
    }
    __syncthreads();
  }

#pragma unroll
  for (int t = 0; t < 2; ++t) {
    const float th = tanhf(tj[t]);
#pragma unroll
    for (int e = 0; e < 8; ++e) {
      float p = th * gw2[lane * 8 + e];
      for (int off = 32; off; off >>= 1) p += __shfl_xor(p, off);
      if (lane == 0) ll[wave * 2 + t][e] = p;
    }
#pragma unroll
    for (int dd = 0; dd < 4; ++dd) {
      float p = cda[t][dd];
      for (int off = 32; off; off >>= 1) p += __shfl_xor(p, off);
      if (lane == 0) cd[wave * 2 + t][dd] = p;
    }
  }
  __syncthreads();

  if (threadIdx.x < RT_TPB) {
    const int t = threadIdx.x;
    const int gtok = tok0 + t;
    float l[8];
#pragma unroll
    for (int e = 0; e < 8; ++e) l[e] = ll[t][e];
#pragma unroll
    for (int e = 0; e < 8; ++e) logits_out[(size_t)gtok * 8 + e] = l[e];
    float m = l[0];
#pragma unroll
    for (int e = 1; e < 8; ++e) m = fmaxf(m, l[e]);
    float p[8], s = 0.f;
#pragma unroll
    for (int e = 0; e < 8; ++e) { p[e] = expf(l[e] - m); s += p[e]; }
#pragma unroll
    for (int e = 0; e < 8; ++e) p[e] /= s;
    int i1 = 0;
#pragma unroll
    for (int e = 1; e < 8; ++e) if (p[e] > p[i1]) i1 = e;
    int i2 = -1;
#pragma unroll
    for (int e = 0; e < 8; ++e) {
      if (e == i1) continue;
      if (i2 < 0 || p[e] > p[i2]) i2 = e;
    }
    float w1 = (i1 == 7) ? 0.f : p[i1];
    float w2 = (i2 == 7) ? 0.f : p[i2];
    const float nrm = w1 + w2;
    w1 /= nrm; w2 /= nrm;
    float pe[8];
#pragma unroll
    for (int e = 0; e < 8; ++e) pe[e] = 0.f;
    pe[i1] += w1; pe[i2] += w2;
    const float cw00 = 1.f / (1.f + expf(cd[t][1] - cd[t][0]));
    const float cw10 = 1.f / (1.f + expf(cd[t][3] - cd[t][2]));
    coef[gtok * 4 + 0] = pe[0] + pe[2] * cw00 + pe[3] * cw10;
    coef[gtok * 4 + 1] = pe[2] * (1.f - cw00);
    coef[gtok * 4 + 2] = pe[3] * (1.f - cw10);
    coef[gtok * 4 + 3] = pe[4] + pe[5] + pe[6] + pe[7];
  }
}

// ============================================================================
// GEMM1: 256x256 tile, BK=64, 8 waves (2Mx4N), 4-phase/K-tile schedule with
// counted vmcnt (T2+T3+T4+T5). LDS 128 KiB double-buffered; XOR-quarter
// swizzle (q ^ (row&7)) applied via pre-swizzled global source (linear
// global_load_lds dest) and matching swizzled ds_read addresses.
// Per-wave output: rows {wm*64..+63} U {128+wm*64..+63},
//                  cols {wn*32..+31} U {128+wn*32..+31}  -> each phase touches
// exactly one A-half and one B-half of the LDS tile, enabling the rolling
// half-tile stage schedule:
//   ph1: rd A0+B0, stage B1(t+1) | ph2: rd B1, stage A0(t+2)
//   ph3: rd A1,    stage B0(t+2) | ph4: stage A1(t+2), s_waitcnt vmcnt(6)
// Steady state keeps 3 half-tiles (6 loads/wave) in flight; never vmcnt(0)
// in the main loop. Epilogue fuses silu(g)*u on the interleaved g/u columns.
// ============================================================================
__global__ __launch_bounds__(512, 2) void gemm1_gu_silu(const short* __restrict__ A,
                                                        const short* __restrict__ Bt,
                                                        short* __restrict__ H,
                                                        int K, int lda, int ldb) {
  __shared__ __align__(16) short As[2][256 * 64];
  __shared__ __align__(16) short Bs[2][256 * 64];

  const int wave = threadIdx.x >> 6;
  const int lane = threadIdx.x & 63;
  const int wm64 = (wave >> 2) * 64;    // wave_m * 64
  const int wn32 = (wave & 3) * 32;     // wave_n * 32
  const int l15 = lane & 15;
  const int quad = lane >> 4;
  const int rq = l15 & 7;
  const int qoff0 = (quad ^ rq) * 8;          // kk=0 swizzled quarter (elems)
  const int qoff1 = ((4 + quad) ^ rq) * 8;    // kk=1

  // staging geometry: wave stages 8 rows x 64 elems per global_load_lds
  const int srow = lane >> 3;
  const int scol = ((lane & 7) ^ srow) * 8;   // pre-swizzled global quarter

  // XCD-aware swizzle (nwg = 1024, divisible by 8)
  const int cpx = gridDim.x >> 3;
  const int wg = ((int)blockIdx.x & 7) * cpx + ((int)blockIdx.x >> 3);
  const int m0 = (wg & 15) * 256;
  const int n0 = (wg >> 4) * 256;

  const short* pA = A + (size_t)(m0 + wave * 16 + srow) * lda + scol;
  const short* pB = Bt + (size_t)(n0 + wave * 16 + srow) * ldb + scol;

  floatx4 acc[8][4];
#pragma unroll
  for (int i = 0; i < 8; ++i)
#pragma unroll
    for (int j = 0; j < 4; ++j) acc[i][j] = (floatx4)0.f;

  short8v a[4][2];   // current A m-block (4 m-frags x 2 ksteps)
  short8v b[4][2];   // b[0..1]=n-frags 0-1 (half0), b[2..3]=n-frags 2-3 (half1)

#define STAGE_A(buf, half, k0)                                                  \
  {                                                                             \
    _Pragma("unroll") for (int g = 0; g < 2; ++g)                               \
        gload_lds16(pA + (size_t)((half) * 128 + g * 8) * lda + (k0),           \
                    &As[buf][((half) * 128 + wave * 16 + g * 8) * 64]);         \
  }
#define STAGE_B(buf, half, k0)                                                  \
  {                                                                             \
    _Pragma("unroll") for (int g = 0; g < 2; ++g)                               \
        gload_lds16(pB + (size_t)((half) * 128 + g * 8) * ldb + (k0),           \
                    &Bs[buf][((half) * 128 + wave * 16 + g * 8) * 64]);         \
  }
#define READ_A(buf, half)                                                       \
  {                                                                             \
    _Pragma("unroll") for (int mi = 0; mi < 4; ++mi) {                          \
      const int r = (half) * 128 + wm64 + mi * 16 + l15;                        \
      a[mi][0] = *(const short8v*)&As[buf][r * 64 + qoff0];                     \
      a[mi][1] = *(const short8v*)&As[buf][r * 64 + qoff1];                     \
    }                                                                           \
  }
#define READ_B(buf, half)                                                       \
  {                                                                             \
    _Pragma("unroll") for (int ni = 0; ni < 2; ++ni) {                          \
      const int r = (half) * 128 + wn32 + ni * 16 + l15;                        \
      b[(half) * 2 + ni][0] = *(const short8v*)&Bs[buf][r * 64 + qoff0];        \
      b[(half) * 2 + ni][1] = *(const short8v*)&Bs[buf][r * 64 + qoff1];        \
    }                                                                           \
  }
#define MFMA_Q(mh, nh)                                                          \
  {                                                                             \
    __builtin_amdgcn_s_setprio(1);                                              \
    _Pragma("unroll") for (int kk = 0; kk < 2; ++kk)                            \
    _Pragma("unroll") for (int mi = 0; mi < 4; ++mi)                            \
    _Pragma("unroll") for (int ni = 0; ni < 2; ++ni)                            \
        acc[(mh) * 4 + mi][(nh) * 2 + ni] = __builtin_amdgcn_mfma_f32_16x16x32_bf16( \
            a[mi][kk], b[(nh) * 2 + ni][kk], acc[(mh) * 4 + mi][(nh) * 2 + ni], \
            0, 0, 0);                                                           \
    __builtin_amdgcn_s_setprio(0);                                              \
  }
#define BAR __builtin_amdgcn_s_barrier()
#define LGKM0 asm volatile("s_waitcnt lgkmcnt(0)" ::: "memory")
#define VMC(n) asm volatile("s_waitcnt vmcnt(" #n ")" ::: "memory")

  // MODE 0: steady state; MODE 1: tile NT-2 (only stage B1(t+1), drain);
  // MODE 2: last tile (no stages, no waits).
#define KTILE(t, MODE)                                                          \
  {                                                                             \
    const int buf = (t) & 1, nbuf = buf ^ 1;                                    \
    const int k1 = ((t) + 1) * 64, k2 = ((t) + 2) * 64;                         \
    (void)k1; (void)k2; (void)nbuf;                                             \
    /* phase 1 */                                                               \
    READ_A(buf, 0); READ_B(buf, 0);                                             \
    if (MODE <= 1) STAGE_B(nbuf, 1, k1);                                        \
    BAR; LGKM0; MFMA_Q(0, 0); BAR;                                              \
    /* phase 2 */                                                               \
    READ_B(buf, 1);                                                             \
    if (MODE == 0) STAGE_A(buf, 0, k2);                                         \
    BAR; LGKM0; MFMA_Q(0, 1); BAR;                                              \
    /* phase 3 */                                                               \
    READ_A(buf, 1);                                                             \
    if (MODE == 0) STAGE_B(buf, 0, k2);                                         \
    BAR; LGKM0; MFMA_Q(1, 0); BAR;                                              \
    /* phase 4 */                                                               \
    if (MODE == 0) { STAGE_A(buf, 1, k2); VMC(6); }                             \
    if (MODE == 1) { VMC(0); }                                                  \
    BAR; MFMA_Q(1, 1); BAR;                                                     \
  }

  // Prologue: tile 0 fully + A0/B0/A1 of tile 1 (issue order = retirement
  // order assumed by the steady-state vmcnt(6) accounting).
  STAGE_A(0, 0, 0); STAGE_A(0, 1, 0); STAGE_B(0, 0, 0); STAGE_B(0, 1, 0);
  STAGE_A(1, 0, 64); STAGE_B(1, 0, 64); STAGE_A(1, 1, 64);
  VMC(6);   // oldest 8 loads (= all of tile 0) complete
  BAR;

  const int NT = K >> 6;
  for (int t = 0; t < NT - 2; ++t) KTILE(t, 0);
  KTILE(NT - 2, 1);
  KTILE(NT - 1, 2);

#undef KTILE
#undef STAGE_A
#undef STAGE_B
#undef READ_A
#undef READ_B
#undef MFMA_Q

  // Epilogue: silu(g)*u on interleaved even/odd columns, write H bf16.
  const int q4 = quad * 4;
#pragma unroll
  for (int mi = 0; mi < 8; ++mi) {
    const int row0 = m0 + (mi >> 2) * 128 + wm64 + (mi & 3) * 16 + q4;
#pragma unroll
    for (int ni = 0; ni < 4; ++ni) {
      const int col = n0 + (ni >> 1) * 128 + wn32 + (ni & 1) * 16 + l15;
#pragma unroll
      for (int rg = 0; rg < 4; ++rg) {
        const float v = acc[mi][ni][rg];
        const float p = __shfl_xor(v, 1);   // partner (g<->u)
        if ((l15 & 1) == 0) {
          const float hv = (v / (1.f + __expf(-v))) * p;  // silu(g)*u
          H[(size_t)(row0 + rg) * DI + (col >> 1)] = f2b(hv);
        }
      }
    }
  }
}

// ---------------- bf16 MFMA GEMM mainloop (128x128, BK=64) — GEMM2 ----------
__device__ __forceinline__ void gemm_mainloop(const short* __restrict__ A,
                                              const short* __restrict__ Bt,
                                              int K, int lda, int ldb,
                                              int m0, int n0,
                                              short* As, short* Bs,
                                              floatx4 (&acc)[4][4]) {
  const int wave = threadIdx.x >> 6;
  const int lane = threadIdx.x & 63;
  const int srow = lane >> 3;                   // row within 8-row staging chunk
  const int scol = ((lane & 7) ^ srow) * 8;     // swizzled source quarter (elems)
  const int wm = (wave & 1) * 64;
  const int wn = (wave >> 1) * 64;
  const int l15 = lane & 15;
  const int quad = lane >> 4;
  const int q0 = ((quad ^ (l15 & 7)) * 8);      // kk=0 read quarter offset (elems)

  for (int k0 = 0; k0 < K; k0 += 64) {
#pragma unroll
    for (int q = 0; q < 4; ++q) {
      const int chunk = wave * 4 + q;           // 16 chunks x 8 rows = 128 rows
      const int row = chunk * 8 + srow;
      gload_lds16(A + (size_t)(m0 + row) * lda + k0 + scol, &As[chunk * 8 * 64]);
      gload_lds16(Bt + (size_t)(n0 + row) * ldb + k0 + scol, &Bs[chunk * 8 * 64]);
    }
    __syncthreads();
#pragma unroll
    for (int kk = 0; kk < 2; ++kk) {
      const int qo = q0 ^ (kk * 32);            // (kk*4+quad)^(l15&7) in elems
      short8v af[4], bf[4];
#pragma unroll
      for (int i = 0; i < 4; ++i) {
        af[i] = *(const short8v*)&As[(wm + i * 16 + l15) * 64 + qo];
        bf[i] = *(const short8v*)&Bs[(wn + i * 16 + l15) * 64 + qo];
      }
#pragma unroll
      for (int mi = 0; mi < 4; ++mi)
#pragma unroll
        for (int ni = 0; ni < 4; ++ni)
          acc[mi][ni] = __builtin_amdgcn_mfma_f32_16x16x32_bf16(af[mi], bf[ni],
                                                                acc[mi][ni], 0, 0, 0);
    }
    __syncthreads();
  }
}

// GEMM2 with fused MoE epilogue.
__global__ __launch_bounds__(256) void gemm_bt_moe(const short* __restrict__ A,
                                                   const short* __restrict__ Bt,
                                                   float* __restrict__ out,
                                                   const float* __restrict__ x,
                                                   const float* __restrict__ cc,
                                                   const float* __restrict__ coef,
                                                   int K, int lda, int ldb) {
  __shared__ short As[128 * 64];
  __shared__ short Bs[128 * 64];
  floatx4 acc[4][4];
#pragma unroll
  for (int a = 0; a < 4; ++a)
#pragma unroll
    for (int b = 0; b < 4; ++b) acc[a][b] = (floatx4)0.0f;
  const int lin = blockIdx.y * gridDim.x + blockIdx.x;
  const int m0 = (lin & 31) * 128, n0 = (lin >> 5) * 128;
  gemm_mainloop(A, Bt, K, lda, ldb, m0, n0, As, Bs, acc);
  const int wave = threadIdx.x >> 6, lane = threadIdx.x & 63;
  const int wm = (wave & 1) * 64, wn = (wave >> 1) * 64;
  const int l15 = lane & 15, q4 = (lane >> 4) * 4;
#pragma unroll
  for (int mi = 0; mi < 4; ++mi) {
    const int row0 = m0 + wm + mi * 16 + q4;
#pragma unroll
    for (int ni = 0; ni < 4; ++ni) {
      const int col = n0 + wn + ni * 16 + l15;
      const float c0v = cc[col];
      const float c1v = cc[DH + col];
#pragma unroll
      for (int rg = 0; rg < 4; ++rg) {
        const int row = row0 + rg;
        const floatx4 cf = *(const floatx4*)&coef[row * 4];
        out[(size_t)row * DH + col] =
            cf[0] * x[(size_t)row * DH + col] + cf[1] * c0v + cf[2] * c1v +
            cf[3] * acc[mi][ni][rg];
      }
    }
  }
}

extern "C" void kernel_launch(void* const* d_in, const int* in_sizes, int n_in,
                              void* d_out, int out_size, void* d_ws, size_t ws_size,
                              hipStream_t stream) {
  const float* x   = (const float*)d_in[0];
  const float* gw1 = (const float*)d_in[1];
  const float* gw2 = (const float*)d_in[2];
  const float* cwg = (const float*)d_in[3];
  const float* cc  = (const float*)d_in[4];
  const float* wg  = (const float*)d_in[5];
  const float* wu  = (const float*)d_in[6];
  const float* wd  = (const float*)d_in[7];
  float* out = (float*)d_out;
  float* logits_out = out + (size_t)TOKS * DH;

  char* ws = (char*)d_ws;
  short* xb    = (short*)(ws);                          // 16.78 MB
  short* wgwuT = (short*)(ws + 16777216);               // [16384][2048] bf16 interleaved
  short* wdT   = (short*)(ws + 16777216 + 67108864);    // [2048][8192] bf16
  short* H     = (short*)(ws + 117440512);              // [4096][8192] bf16
  float* coef  = (float*)(ws + 117440512 + 67108864);   // [4096][4] fp32

  cvt_f32_to_bf16<<<(TOKS * DH) / (256 * 4), 256, 0, stream>>>(x, xb);
  transpose_to_bf16<<<dim3(DI / 32, DH / 32), 256, 0, stream>>>(wg, wgwuT, DH, DI, 2, 0);
  transpose_to_bf16<<<dim3(DI / 32, DH / 32), 256, 0, stream>>>(wu, wgwuT, DH, DI, 2, 1);
  transpose_to_bf16<<<dim3(DH / 32, DI / 32), 256, 0, stream>>>(wd, wdT, DI, DH, 1, 0);
  router_kernel<<<TOKS / RT_TPB, 256, 0, stream>>>(x, gw1, gw2, cwg, logits_out, coef);
  // 256x256 tiles: 16 m-tiles x 64 n-tiles = 1024 wgs, 512 threads
  gemm1_gu_silu<<<dim3((TOKS / 256) * ((2 * DI) / 256)), 512, 0, stream>>>(
      xb, wgwuT, H, DH, DH, DH);
  gemm_bt_moe<<<dim3(DH / 128, TOKS / 128), 256, 0, stream>>>(
      H, wdT, out, x, cc, coef, DI, DI, DI);
}

// Round 2
// 806.944 us; speedup vs baseline: 1.0684x; 1.0476x over previous
//
#include <hip/hip_runtime.h>
#include <stdint.h>
#include <stddef.h>

#define TOKS 4096
#define DH   2048
#define DI   8192

typedef __attribute__((ext_vector_type(8))) short short8v;
typedef __attribute__((ext_vector_type(4))) short short4v;
typedef __attribute__((ext_vector_type(4))) float floatx4;

__device__ __forceinline__ float b2f(short s) {
  union { unsigned u; float f; } v;
  v.u = ((unsigned)(unsigned short)s) << 16;
  return v.f;
}
__device__ __forceinline__ short f2b(float f) {
  union { float f; unsigned u; } v; v.f = f;
  unsigned r = (v.u + 0x7fffu + ((v.u >> 16) & 1u)) >> 16;  // RNE
  return (short)(unsigned short)r;
}
__device__ __forceinline__ void gload_lds16(const void* g, void* l) {
  __builtin_amdgcn_global_load_lds((const __attribute__((address_space(1))) void*)g,
                                   (__attribute__((address_space(3))) void*)l, 16, 0, 0);
}

// ---------------- fp32 -> bf16 elementwise (x) ----------------
__global__ __launch_bounds__(256) void cvt_f32_to_bf16(const float* __restrict__ in,
                                                       short* __restrict__ out) {
  size_t i = (size_t)blockIdx.x * 256 + threadIdx.x;
  floatx4 v = *(const floatx4*)&in[i * 4];
  short4v o;
  o[0] = f2b(v[0]); o[1] = f2b(v[1]); o[2] = f2b(v[2]); o[3] = f2b(v[3]);
  *(short4v*)&out[i * 4] = o;
}

// ---------- fp32 [K][N] -> bf16 [N][K] transpose (strided/interleaved out) ----
__global__ __launch_bounds__(256) void transpose_to_bf16(const float* __restrict__ in,
                                                         short* __restrict__ out,
                                                         int K, int N,
                                                         int rstride, int roff) {
  __shared__ float tile[32][33];
  const int n0 = blockIdx.x * 32, k0 = blockIdx.y * 32;
  const int tx = threadIdx.x & 31, ty = threadIdx.x >> 5;  // ty: 0..7
#pragma unroll
  for (int yy = 0; yy < 32; yy += 8)
    tile[ty + yy][tx] = in[(size_t)(k0 + ty + yy) * N + n0 + tx];
  __syncthreads();
#pragma unroll
  for (int yy = 0; yy < 32; yy += 8)
    out[((size_t)(n0 + ty + yy) * rstride + roff) * K + k0 + tx] = f2b(tile[tx][ty + yy]);
}

// ---------------- router + const-expert gates (fp32 exact) ----------------
#define RT_TPB 8
__global__ __launch_bounds__(256) void router_kernel(const float* __restrict__ x,
                                                     const float* __restrict__ gw1,
                                                     const float* __restrict__ gw2,
                                                     const float* __restrict__ cwg,
                                                     float* __restrict__ logits_out,
                                                     float* __restrict__ coef) {
  const int wave = threadIdx.x >> 6, lane = threadIdx.x & 63;
  const int tok0 = blockIdx.x * RT_TPB;
  __shared__ float xs[RT_TPB][512];   // 16 KB chunk
  __shared__ float ll[RT_TPB][8];
  __shared__ float cd[RT_TPB][4];

  float tj[2] = {0.f, 0.f};           // gate-hidden partial, col = lane
  float cda[2][4] = {{0.f,0.f,0.f,0.f},{0.f,0.f,0.f,0.f}};  // const-dot partials

  const int st = threadIdx.x >> 5;        // staging token 0..7
  const int sl = threadIdx.x & 31;

  for (int c = 0; c < 4; ++c) {
    const int dbase = c * 512;
#pragma unroll
    for (int r = 0; r < 4; ++r) {
      const int idx = r * 128 + sl * 4;
      *(floatx4*)&xs[st][idx] = *(const floatx4*)&x[(size_t)(tok0 + st) * DH + dbase + idx];
    }
    __syncthreads();
    for (int d = 0; d < 512; ++d) {
      const float g = gw1[(size_t)(dbase + d) * 64 + lane];
      tj[0] += xs[wave * 2 + 0][d] * g;
      tj[1] += xs[wave * 2 + 1][d] * g;
    }
#pragma unroll
    for (int dq = 0; dq < 8; ++dq) {
      const int d = dq * 64 + lane;
      const float w0 = cwg[(size_t)(dbase + d) * 2 + 0];
      const float w1 = cwg[(size_t)(dbase + d) * 2 + 1];
      const float w2 = cwg[(size_t)DH * 2 + (dbase + d) * 2 + 0];
      const float w3 = cwg[(size_t)DH * 2 + (dbase + d) * 2 + 1];
#pragma unroll
      for (int t = 0; t < 2; ++t) {
        const float xv = xs[wave * 2 + t][d];
        cda[t][0] += xv * w0; cda[t][1] += xv * w1;
        cda[t][2] += xv * w2; cda[t][3] += xv * w3;
      }
    }
    __syncthreads();
  }

#pragma unroll
  for (int t = 0; t < 2; ++t) {
    const float th = tanhf(tj[t]);
#pragma unroll
    for (int e = 0; e < 8; ++e) {
      float p = th * gw2[lane * 8 + e];
      for (int off = 32; off; off >>= 1) p += __shfl_xor(p, off);
      if (lane == 0) ll[wave * 2 + t][e] = p;
    }
#pragma unroll
    for (int dd = 0; dd < 4; ++dd) {
      float p = cda[t][dd];
      for (int off = 32; off; off >>= 1) p += __shfl_xor(p, off);
      if (lane == 0) cd[wave * 2 + t][dd] = p;
    }
  }
  __syncthreads();

  if (threadIdx.x < RT_TPB) {
    const int t = threadIdx.x;
    const int gtok = tok0 + t;
    float l[8];
#pragma unroll
    for (int e = 0; e < 8; ++e) l[e] = ll[t][e];
#pragma unroll
    for (int e = 0; e < 8; ++e) logits_out[(size_t)gtok * 8 + e] = l[e];
    float m = l[0];
#pragma unroll
    for (int e = 1; e < 8; ++e) m = fmaxf(m, l[e]);
    float p[8], s = 0.f;
#pragma unroll
    for (int e = 0; e < 8; ++e) { p[e] = expf(l[e] - m); s += p[e]; }
#pragma unroll
    for (int e = 0; e < 8; ++e) p[e] /= s;
    int i1 = 0;
#pragma unroll
    for (int e = 1; e < 8; ++e) if (p[e] > p[i1]) i1 = e;
    int i2 = -1;
#pragma unroll
    for (int e = 0; e < 8; ++e) {
      if (e == i1) continue;
      if (i2 < 0 || p[e] > p[i2]) i2 = e;
    }
    float w1 = (i1 == 7) ? 0.f : p[i1];
    float w2 = (i2 == 7) ? 0.f : p[i2];
    const float nrm = w1 + w2;
    w1 /= nrm; w2 /= nrm;
    float pe[8];
#pragma unroll
    for (int e = 0; e < 8; ++e) pe[e] = 0.f;
    pe[i1] += w1; pe[i2] += w2;
    const float cw00 = 1.f / (1.f + expf(cd[t][1] - cd[t][0]));
    const float cw10 = 1.f / (1.f + expf(cd[t][3] - cd[t][2]));
    coef[gtok * 4 + 0] = pe[0] + pe[2] * cw00 + pe[3] * cw10;
    coef[gtok * 4 + 1] = pe[2] * (1.f - cw00);
    coef[gtok * 4 + 2] = pe[3] * (1.f - cw10);
    coef[gtok * 4 + 3] = pe[4] + pe[5] + pe[6] + pe[7];
  }
}

// ============================================================================
// GEMM1: 256x256 tile, BK=64, 8 waves (2Mx4N), **2-phase/K-tile** schedule with
// counted vmcnt. LDS 128 KiB double-buffered; XOR-quarter swizzle via
// pre-swizzled global source (linear global_load_lds dest) + swizzled ds_read.
// Per K-tile (4 barriers, 2 lgkm drains, 1 vmcnt):
//   ph1: rd A0(8)+Ball(8), stage B1(t+1)+A1(t+1) -> other buf, safe
//        BAR; lgkm0; 32 MFMA (m-half0 x all n); BAR
//   ph2: rd A1(8), stage A0(t+2)+B0(t+2) -> cur buf, regions closed at ph1 bar
//        vmcnt(4) [drains B1/A1(t+1), leaves A0/B0(t+2)]; BAR; lgkm0;
//        32 MFMA (m-half1); BAR
// Hazard rule honored: any stage overwriting region R issues only after the
// barrier that closes R's last read. Never vmcnt(0) in the main loop.
// ============================================================================
__global__ __launch_bounds__(512, 2) void gemm1_gu_silu(const short* __restrict__ A,
                                                        const short* __restrict__ Bt,
                                                        short* __restrict__ H,
                                                        int K, int lda, int ldb) {
  __shared__ __align__(16) short As[2][256 * 64];
  __shared__ __align__(16) short Bs[2][256 * 64];

  const int wave = threadIdx.x >> 6;
  const int lane = threadIdx.x & 63;
  const int wm64 = (wave >> 2) * 64;    // wave_m * 64
  const int wn32 = (wave & 3) * 32;     // wave_n * 32
  const int l15 = lane & 15;
  const int quad = lane >> 4;
  const int rq = l15 & 7;
  const int qoff0 = (quad ^ rq) * 8;          // kk=0 swizzled quarter (elems)
  const int qoff1 = ((4 + quad) ^ rq) * 8;    // kk=1

  // staging geometry: wave stages 8 rows x 64 elems per global_load_lds
  const int srow = lane >> 3;
  const int scol = ((lane & 7) ^ srow) * 8;   // pre-swizzled global quarter

  // XCD-aware swizzle (nwg = 1024, divisible by 8)
  const int cpx = gridDim.x >> 3;
  const int wg = ((int)blockIdx.x & 7) * cpx + ((int)blockIdx.x >> 3);
  const int m0 = (wg & 15) * 256;
  const int n0 = (wg >> 4) * 256;

  const short* pA = A + (size_t)(m0 + wave * 16 + srow) * lda + scol;
  const short* pB = Bt + (size_t)(n0 + wave * 16 + srow) * ldb + scol;

  floatx4 acc[8][4];
#pragma unroll
  for (int i = 0; i < 8; ++i)
#pragma unroll
    for (int j = 0; j < 4; ++j) acc[i][j] = (floatx4)0.f;

  short8v a[4][2];   // current A m-half (4 m-frags x 2 ksteps)
  short8v b[4][2];   // all 4 n-frags (b[0..1]=col-half0, b[2..3]=col-half1)

#define STAGE_A(buf, half, k0)                                                  \
  {                                                                             \
    _Pragma("unroll") for (int g = 0; g < 2; ++g)                               \
        gload_lds16(pA + (size_t)((half) * 128 + g * 8) * lda + (k0),           \
                    &As[buf][((half) * 128 + wave * 16 + g * 8) * 64]);         \
  }
#define STAGE_B(buf, half, k0)                                                  \
  {                                                                             \
    _Pragma("unroll") for (int g = 0; g < 2; ++g)                               \
        gload_lds16(pB + (size_t)((half) * 128 + g * 8) * ldb + (k0),           \
                    &Bs[buf][((half) * 128 + wave * 16 + g * 8) * 64]);         \
  }
#define READ_A(buf, half)                                                       \
  {                                                                             \
    _Pragma("unroll") for (int mi = 0; mi < 4; ++mi) {                          \
      const int r = (half) * 128 + wm64 + mi * 16 + l15;                        \
      a[mi][0] = *(const short8v*)&As[buf][r * 64 + qoff0];                     \
      a[mi][1] = *(const short8v*)&As[buf][r * 64 + qoff1];                     \
    }                                                                           \
  }
#define READ_BALL(buf)                                                          \
  {                                                                             \
    _Pragma("unroll") for (int h = 0; h < 2; ++h)                               \
    _Pragma("unroll") for (int ni = 0; ni < 2; ++ni) {                          \
      const int r = h * 128 + wn32 + ni * 16 + l15;                             \
      b[h * 2 + ni][0] = *(const short8v*)&Bs[buf][r * 64 + qoff0];             \
      b[h * 2 + ni][1] = *(const short8v*)&Bs[buf][r * 64 + qoff1];             \
    }                                                                           \
  }
#define MFMA_H(mh)                                                              \
  {                                                                             \
    __builtin_amdgcn_s_setprio(1);                                              \
    _Pragma("unroll") for (int kk = 0; kk < 2; ++kk)                            \
    _Pragma("unroll") for (int mi = 0; mi < 4; ++mi)                            \
    _Pragma("unroll") for (int ni = 0; ni < 4; ++ni)                            \
        acc[(mh) * 4 + mi][ni] = __builtin_amdgcn_mfma_f32_16x16x32_bf16(       \
            a[mi][kk], b[ni][kk], acc[(mh) * 4 + mi][ni], 0, 0, 0);             \
    __builtin_amdgcn_s_setprio(0);                                              \
  }
#define BAR __builtin_amdgcn_s_barrier()
#define LGKM0 asm volatile("s_waitcnt lgkmcnt(0)" ::: "memory")
#define VMC(n) asm volatile("s_waitcnt vmcnt(" #n ")" ::: "memory")

  // MODE 0: steady; MODE 1: tile NT-2 (stage only B1/A1(t+1), drain vmcnt 0);
  // MODE 2: last tile (no stages, no waits).
#define KTILE(t, MODE)                                                          \
  {                                                                             \
    const int buf = (t) & 1, nbuf = buf ^ 1;                                    \
    const int k1 = ((t) + 1) * 64, k2 = ((t) + 2) * 64;                         \
    (void)k1; (void)k2; (void)nbuf;                                             \
    /* phase 1: m-half0 */                                                      \
    READ_A(buf, 0); READ_BALL(buf);                                             \
    if (MODE <= 1) { STAGE_B(nbuf, 1, k1); STAGE_A(nbuf, 1, k1); }              \
    BAR; LGKM0; MFMA_H(0); BAR;                                                 \
    /* phase 2: m-half1 */                                                      \
    READ_A(buf, 1);                                                             \
    if (MODE == 0) { STAGE_A(buf, 0, k2); STAGE_B(buf, 0, k2); VMC(4); }        \
    if (MODE == 1) { VMC(0); }                                                  \
    BAR; LGKM0; MFMA_H(1); BAR;                                                 \
  }

  // Prologue: tile0 fully + A0/B0 of tile 1. Issue order matters for vmcnt:
  // [A0(0) B0(0) B1(0) A1(0)] then [A0(1) B0(1)] -> VMC(4) completes tile 0.
  STAGE_A(0, 0, 0); STAGE_B(0, 0, 0); STAGE_B(0, 1, 0); STAGE_A(0, 1, 0);
  STAGE_A(1, 0, 64); STAGE_B(1, 0, 64);
  VMC(4);
  BAR;

  const int NT = K >> 6;
  for (int t = 0; t < NT - 2; ++t) KTILE(t, 0);
  KTILE(NT - 2, 1);
  KTILE(NT - 1, 2);

#undef KTILE
#undef STAGE_A
#undef STAGE_B
#undef READ_A
#undef READ_BALL
#undef MFMA_H

  // Epilogue: silu(g)*u on interleaved even/odd columns, write H bf16.
  const int q4 = quad * 4;
#pragma unroll
  for (int mi = 0; mi < 8; ++mi) {
    const int row0 = m0 + (mi >> 2) * 128 + wm64 + (mi & 3) * 16 + q4;
#pragma unroll
    for (int ni = 0; ni < 4; ++ni) {
      const int col = n0 + (ni >> 1) * 128 + wn32 + (ni & 1) * 16 + l15;
#pragma unroll
      for (int rg = 0; rg < 4; ++rg) {
        const float v = acc[mi][ni][rg];
        const float p = __shfl_xor(v, 1);   // partner (g<->u)
        if ((l15 & 1) == 0) {
          const float hv = (v / (1.f + __expf(-v))) * p;  // silu(g)*u
          H[(size_t)(row0 + rg) * DI + (col >> 1)] = f2b(hv);
        }
      }
    }
  }
}

// ---------------- bf16 MFMA GEMM mainloop (128x128, BK=64) — GEMM2 ----------
__device__ __forceinline__ void gemm_mainloop(const short* __restrict__ A,
                                              const short* __restrict__ Bt,
                                              int K, int lda, int ldb,
                                              int m0, int n0,
                                              short* As, short* Bs,
                                              floatx4 (&acc)[4][4]) {
  const int wave = threadIdx.x >> 6;
  const int lane = threadIdx.x & 63;
  const int srow = lane >> 3;                   // row within 8-row staging chunk
  const int scol = ((lane & 7) ^ srow) * 8;     // swizzled source quarter (elems)
  const int wm = (wave & 1) * 64;
  const int wn = (wave >> 1) * 64;
  const int l15 = lane & 15;
  const int quad = lane >> 4;
  const int q0 = ((quad ^ (l15 & 7)) * 8);      // kk=0 read quarter offset (elems)

  for (int k0 = 0; k0 < K; k0 += 64) {
#pragma unroll
    for (int q = 0; q < 4; ++q) {
      const int chunk = wave * 4 + q;           // 16 chunks x 8 rows = 128 rows
      const int row = chunk * 8 + srow;
      gload_lds16(A + (size_t)(m0 + row) * lda + k0 + scol, &As[chunk * 8 * 64]);
      gload_lds16(Bt + (size_t)(n0 + row) * ldb + k0 + scol, &Bs[chunk * 8 * 64]);
    }
    __syncthreads();
#pragma unroll
    for (int kk = 0; kk < 2; ++kk) {
      const int qo = q0 ^ (kk * 32);            // (kk*4+quad)^(l15&7) in elems
      short8v af[4], bf[4];
#pragma unroll
      for (int i = 0; i < 4; ++i) {
        af[i] = *(const short8v*)&As[(wm + i * 16 + l15) * 64 + qo];
        bf[i] = *(const short8v*)&Bs[(wn + i * 16 + l15) * 64 + qo];
      }
#pragma unroll
      for (int mi = 0; mi < 4; ++mi)
#pragma unroll
        for (int ni = 0; ni < 4; ++ni)
          acc[mi][ni] = __builtin_amdgcn_mfma_f32_16x16x32_bf16(af[mi], bf[ni],
                                                                acc[mi][ni], 0, 0, 0);
    }
    __syncthreads();
  }
}

// GEMM2 with fused MoE epilogue.
__global__ __launch_bounds__(256) void gemm_bt_moe(const short* __restrict__ A,
                                                   const short* __restrict__ Bt,
                                                   float* __restrict__ out,
                                                   const float* __restrict__ x,
                                                   const float* __restrict__ cc,
                                                   const float* __restrict__ coef,
                                                   int K, int lda, int ldb) {
  __shared__ short As[128 * 64];
  __shared__ short Bs[128 * 64];
  floatx4 acc[4][4];
#pragma unroll
  for (int a = 0; a < 4; ++a)
#pragma unroll
    for (int b = 0; b < 4; ++b) acc[a][b] = (floatx4)0.0f;
  const int lin = blockIdx.y * gridDim.x + blockIdx.x;
  const int m0 = (lin & 31) * 128, n0 = (lin >> 5) * 128;
  gemm_mainloop(A, Bt, K, lda, ldb, m0, n0, As, Bs, acc);
  const int wave = threadIdx.x >> 6, lane = threadIdx.x & 63;
  const int wm = (wave & 1) * 64, wn = (wave >> 1) * 64;
  const int l15 = lane & 15, q4 = (lane >> 4) * 4;
#pragma unroll
  for (int mi = 0; mi < 4; ++mi) {
    const int row0 = m0 + wm + mi * 16 + q4;
#pragma unroll
    for (int ni = 0; ni < 4; ++ni) {
      const int col = n0 + wn + ni * 16 + l15;
      const float c0v = cc[col];
      const float c1v = cc[DH + col];
#pragma unroll
      for (int rg = 0; rg < 4; ++rg) {
        const int row = row0 + rg;
        const floatx4 cf = *(const floatx4*)&coef[row * 4];
        out[(size_t)row * DH + col] =
            cf[0] * x[(size_t)row * DH + col] + cf[1] * c0v + cf[2] * c1v +
            cf[3] * acc[mi][ni][rg];
      }
    }
  }
}

extern "C" void kernel_launch(void* const* d_in, const int* in_sizes, int n_in,
                              void* d_out, int out_size, void* d_ws, size_t ws_size,
                              hipStream_t stream) {
  const float* x   = (const float*)d_in[0];
  const float* gw1 = (const float*)d_in[1];
  const float* gw2 = (const float*)d_in[2];
  const float* cwg = (const float*)d_in[3];
  const float* cc  = (const float*)d_in[4];
  const float* wg  = (const float*)d_in[5];
  const float* wu  = (const float*)d_in[6];
  const float* wd  = (const float*)d_in[7];
  float* out = (float*)d_out;
  float* logits_out = out + (size_t)TOKS * DH;

  char* ws = (char*)d_ws;
  short* xb    = (short*)(ws);                          // 16.78 MB
  short* wgwuT = (short*)(ws + 16777216);               // [16384][2048] bf16 interleaved
  short* wdT   = (short*)(ws + 16777216 + 67108864);    // [2048][8192] bf16
  short* H     = (short*)(ws + 117440512);              // [4096][8192] bf16
  float* coef  = (float*)(ws + 117440512 + 67108864);   // [4096][4] fp32

  cvt_f32_to_bf16<<<(TOKS * DH) / (256 * 4), 256, 0, stream>>>(x, xb);
  transpose_to_bf16<<<dim3(DI / 32, DH / 32), 256, 0, stream>>>(wg, wgwuT, DH, DI, 2, 0);
  transpose_to_bf16<<<dim3(DI / 32, DH / 32), 256, 0, stream>>>(wu, wgwuT, DH, DI, 2, 1);
  transpose_to_bf16<<<dim3(DH / 32, DI / 32), 256, 0, stream>>>(wd, wdT, DI, DH, 1, 0);
  router_kernel<<<TOKS / RT_TPB, 256, 0, stream>>>(x, gw1, gw2, cwg, logits_out, coef);
  // 256x256 tiles: 16 m-tiles x 64 n-tiles = 1024 wgs, 512 threads
  gemm1_gu_silu<<<dim3((TOKS / 256) * ((2 * DI) / 256)), 512, 0, stream>>>(
      xb, wgwuT, H, DH, DH, DH);
  gemm_bt_moe<<<dim3(DH / 128, TOKS / 128), 256, 0, stream>>>(
      H, wdT, out, x, cc, coef, DI, DI, DI);
}

// Round 4
// 791.127 us; speedup vs baseline: 1.0897x; 1.0200x over previous
//
#include <hip/hip_runtime.h>
#include <stdint.h>
#include <stddef.h>

#define TOKS 4096
#define DH   2048
#define DI   8192

typedef __attribute__((ext_vector_type(8))) short short8v;
typedef __attribute__((ext_vector_type(4))) short short4v;
typedef __attribute__((ext_vector_type(4))) float floatx4;

__device__ __forceinline__ float b2f(short s) {
  union { unsigned u; float f; } v;
  v.u = ((unsigned)(unsigned short)s) << 16;
  return v.f;
}
__device__ __forceinline__ short f2b(float f) {
  union { float f; unsigned u; } v; v.f = f;
  unsigned r = (v.u + 0x7fffu + ((v.u >> 16) & 1u)) >> 16;  // RNE
  return (short)(unsigned short)r;
}
__device__ __forceinline__ void gload_lds16(const void* g, void* l) {
  __builtin_amdgcn_global_load_lds((const __attribute__((address_space(1))) void*)g,
                                   (__attribute__((address_space(3))) void*)l, 16, 0, 0);
}

// ---------------- fp32 -> bf16 elementwise (x) ----------------
__global__ __launch_bounds__(256) void cvt_f32_to_bf16(const float* __restrict__ in,
                                                       short* __restrict__ out) {
  size_t i = (size_t)blockIdx.x * 256 + threadIdx.x;
  floatx4 v = *(const floatx4*)&in[i * 4];
  short4v o;
  o[0] = f2b(v[0]); o[1] = f2b(v[1]); o[2] = f2b(v[2]); o[3] = f2b(v[3]);
  *(short4v*)&out[i * 4] = o;
}

// ---------- fp32 [K][N] -> bf16 [N][K] transpose (strided/interleaved out) ----
__global__ __launch_bounds__(256) void transpose_to_bf16(const float* __restrict__ in,
                                                         short* __restrict__ out,
                                                         int K, int N,
                                                         int rstride, int roff) {
  __shared__ float tile[32][33];
  const int n0 = blockIdx.x * 32, k0 = blockIdx.y * 32;
  const int tx = threadIdx.x & 31, ty = threadIdx.x >> 5;  // ty: 0..7
#pragma unroll
  for (int yy = 0; yy < 32; yy += 8)
    tile[ty + yy][tx] = in[(size_t)(k0 + ty + yy) * N + n0 + tx];
  __syncthreads();
#pragma unroll
  for (int yy = 0; yy < 32; yy += 8)
    out[((size_t)(n0 + ty + yy) * rstride + roff) * K + k0 + tx] = f2b(tile[tx][ty + yy]);
}

// ---------------- router + const-expert gates (fp32 exact) ----------------
#define RT_TPB 8
__global__ __launch_bounds__(256) void router_kernel(const float* __restrict__ x,
                                                     const float* __restrict__ gw1,
                                                     const float* __restrict__ gw2,
                                                     const float* __restrict__ cwg,
                                                     float* __restrict__ logits_out,
                                                     float* __restrict__ coef) {
  const int wave = threadIdx.x >> 6, lane = threadIdx.x & 63;
  const int tok0 = blockIdx.x * RT_TPB;
  __shared__ float xs[RT_TPB][512];   // 16 KB chunk
  __shared__ float ll[RT_TPB][8];
  __shared__ float cd[RT_TPB][4];

  float tj[2] = {0.f, 0.f};           // gate-hidden partial, col = lane
  float cda[2][4] = {{0.f,0.f,0.f,0.f},{0.f,0.f,0.f,0.f}};  // const-dot partials

  const int st = threadIdx.x >> 5;        // staging token 0..7
  const int sl = threadIdx.x & 31;

  for (int c = 0; c < 4; ++c) {
    const int dbase = c * 512;
#pragma unroll
    for (int r = 0; r < 4; ++r) {
      const int idx = r * 128 + sl * 4;
      *(floatx4*)&xs[st][idx] = *(const floatx4*)&x[(size_t)(tok0 + st) * DH + dbase + idx];
    }
    __syncthreads();
    for (int d = 0; d < 512; ++d) {
      const float g = gw1[(size_t)(dbase + d) * 64 + lane];
      tj[0] += xs[wave * 2 + 0][d] * g;
      tj[1] += xs[wave * 2 + 1][d] * g;
    }
#pragma unroll
    for (int dq = 0; dq < 8; ++dq) {
      const int d = dq * 64 + lane;
      const float w0 = cwg[(size_t)(dbase + d) * 2 + 0];
      const float w1 = cwg[(size_t)(dbase + d) * 2 + 1];
      const float w2 = cwg[(size_t)DH * 2 + (dbase + d) * 2 + 0];
      const float w3 = cwg[(size_t)DH * 2 + (dbase + d) * 2 + 1];
#pragma unroll
      for (int t = 0; t < 2; ++t) {
        const float xv = xs[wave * 2 + t][d];
        cda[t][0] += xv * w0; cda[t][1] += xv * w1;
        cda[t][2] += xv * w2; cda[t][3] += xv * w3;
      }
    }
    __syncthreads();
  }

#pragma unroll
  for (int t = 0; t < 2; ++t) {
    const float th = tanhf(tj[t]);
#pragma unroll
    for (int e = 0; e < 8; ++e) {
      float p = th * gw2[lane * 8 + e];
      for (int off = 32; off; off >>= 1) p += __shfl_xor(p, off);
      if (lane == 0) ll[wave * 2 + t][e] = p;
    }
#pragma unroll
    for (int dd = 0; dd < 4; ++dd) {
      float p = cda[t][dd];
      for (int off = 32; off; off >>= 1) p += __shfl_xor(p, off);
      if (lane == 0) cd[wave * 2 + t][dd] = p;
    }
  }
  __syncthreads();

  if (threadIdx.x < RT_TPB) {
    const int t = threadIdx.x;
    const int gtok = tok0 + t;
    float l[8];
#pragma unroll
    for (int e = 0; e < 8; ++e) l[e] = ll[t][e];
#pragma unroll
    for (int e = 0; e < 8; ++e) logits_out[(size_t)gtok * 8 + e] = l[e];
    float m = l[0];
#pragma unroll
    for (int e = 1; e < 8; ++e) m = fmaxf(m, l[e]);
    float p[8], s = 0.f;
#pragma unroll
    for (int e = 0; e < 8; ++e) { p[e] = expf(l[e] - m); s += p[e]; }
#pragma unroll
    for (int e = 0; e < 8; ++e) p[e] /= s;
    int i1 = 0;
#pragma unroll
    for (int e = 1; e < 8; ++e) if (p[e] > p[i1]) i1 = e;
    int i2 = -1;
#pragma unroll
    for (int e = 0; e < 8; ++e) {
      if (e == i1) continue;
      if (i2 < 0 || p[e] > p[i2]) i2 = e;
    }
    float w1 = (i1 == 7) ? 0.f : p[i1];
    float w2 = (i2 == 7) ? 0.f : p[i2];
    const float nrm = w1 + w2;
    w1 /= nrm; w2 /= nrm;
    float pe[8];
#pragma unroll
    for (int e = 0; e < 8; ++e) pe[e] = 0.f;
    pe[i1] += w1; pe[i2] += w2;
    const float cw00 = 1.f / (1.f + expf(cd[t][1] - cd[t][0]));
    const float cw10 = 1.f / (1.f + expf(cd[t][3] - cd[t][2]));
    coef[gtok * 4 + 0] = pe[0] + pe[2] * cw00 + pe[3] * cw10;
    coef[gtok * 4 + 1] = pe[2] * (1.f - cw00);
    coef[gtok * 4 + 2] = pe[3] * (1.f - cw10);
    coef[gtok * 4 + 3] = pe[4] + pe[5] + pe[6] + pe[7];
  }
}

// ============================================================================
// GEMM1: 256x256 tile, BK=64, 8 waves (2Mx4N), 2-phase/K-tile, ONE barrier per
// phase, NO full lgkm drains: ds_reads issued in consumption order, compiler
// emits per-dependency counted lgkmcnt waits -> each wave starts its MFMA burst
// as soon as its first frags return; CU-wide LDS drain overlaps the MFMA burst.
// Hazard invariants (all verified against barrier ordering):
//  - every ds_read is consumed by an MFMA in its own phase => its wait
//    completes before the wave reaches the phase-end barrier => stages after
//    that barrier may overwrite the region.
//  - stage completion visibility: VMC(4) precedes the phase-end barrier one
//    tile before the region is read. Never vmcnt(0) in the main loop.
// ============================================================================
__global__ __launch_bounds__(512, 2) void gemm1_gu_silu(const short* __restrict__ A,
                                                        const short* __restrict__ Bt,
                                                        short* __restrict__ H,
                                                        int K, int lda, int ldb) {
  __shared__ __align__(16) short As[2][256 * 64];
  __shared__ __align__(16) short Bs[2][256 * 64];

  const int wave = threadIdx.x >> 6;
  const int lane = threadIdx.x & 63;
  const int wm64 = (wave >> 2) * 64;    // wave_m * 64
  const int wn32 = (wave & 3) * 32;     // wave_n * 32
  const int l15 = lane & 15;
  const int quad = lane >> 4;
  const int rq = l15 & 7;
  const int qoff0 = (quad ^ rq) * 8;          // kk=0 swizzled quarter (elems)
  const int qoff1 = ((4 + quad) ^ rq) * 8;    // kk=1

  // staging geometry: wave stages 8 rows x 64 elems per global_load_lds
  const int srow = lane >> 3;
  const int scol = ((lane & 7) ^ srow) * 8;   // pre-swizzled global quarter

  // XCD-aware swizzle (nwg = 1024, divisible by 8)
  const int cpx = gridDim.x >> 3;
  const int wg = ((int)blockIdx.x & 7) * cpx + ((int)blockIdx.x >> 3);
  const int m0 = (wg & 15) * 256;
  const int n0 = (wg >> 4) * 256;

  const short* pA = A + (size_t)(m0 + wave * 16 + srow) * lda + scol;
  const short* pB = Bt + (size_t)(n0 + wave * 16 + srow) * ldb + scol;

  floatx4 acc[8][4];
#pragma unroll
  for (int i = 0; i < 8; ++i)
#pragma unroll
    for (int j = 0; j < 4; ++j) acc[i][j] = (floatx4)0.f;

  short8v a[4][2];   // current A m-half (4 m-frags x 2 ksteps)
  short8v b[4][2];   // all 4 n-frags (b[0..1]=col-half0, b[2..3]=col-half1)

#define STAGE_A(buf, half, k0)                                                  \
  {                                                                             \
    _Pragma("unroll") for (int g = 0; g < 2; ++g)                               \
        gload_lds16(pA + (size_t)((half) * 128 + g * 8) * lda + (k0),           \
                    &As[buf][((half) * 128 + wave * 16 + g * 8) * 64]);         \
  }
#define STAGE_B(buf, half, k0)                                                  \
  {                                                                             \
    _Pragma("unroll") for (int g = 0; g < 2; ++g)                               \
        gload_lds16(pB + (size_t)((half) * 128 + g * 8) * ldb + (k0),           \
                    &Bs[buf][((half) * 128 + wave * 16 + g * 8) * 64]);         \
  }
// single-frag reads, issued in MFMA consumption order
#define RD_A(mi, half, kk)                                                      \
  a[mi][kk] = *(const short8v*)&As[buf][((half) * 128 + wm64 + (mi) * 16 + l15) * 64 + ((kk) ? qoff1 : qoff0)]
#define RD_B(j, kk)                                                             \
  b[j][kk] = *(const short8v*)&Bs[buf][(((j) >> 1) * 128 + wn32 + ((j) & 1) * 16 + l15) * 64 + ((kk) ? qoff1 : qoff0)]
#define MFMA_H(mh)                                                              \
  {                                                                             \
    __builtin_amdgcn_s_setprio(1);                                              \
    _Pragma("unroll") for (int kk = 0; kk < 2; ++kk)                            \
    _Pragma("unroll") for (int mi = 0; mi < 4; ++mi)                            \
    _Pragma("unroll") for (int ni = 0; ni < 4; ++ni)                            \
        acc[(mh) * 4 + mi][ni] = __builtin_amdgcn_mfma_f32_16x16x32_bf16(       \
            a[mi][kk], b[ni][kk], acc[(mh) * 4 + mi][ni], 0, 0, 0);             \
    __builtin_amdgcn_s_setprio(0);                                              \
  }
#define FENCE asm volatile("" ::: "memory")
#define BAR do { FENCE; __builtin_amdgcn_s_barrier(); FENCE; } while (0)
#define VMC(n) asm volatile("s_waitcnt vmcnt(" #n ")" ::: "memory")

  // MODE 0: steady; MODE 1: tile NT-2 (stage only B1/A1(t+1), drain vmcnt 0);
  // MODE 2: last tile (no stages, no waits).
#define KTILE(t, MODE)                                                          \
  {                                                                             \
    const int buf = (t) & 1, nbuf = buf ^ 1;                                    \
    const int k1 = ((t) + 1) * 64, k2 = ((t) + 2) * 64;                         \
    (void)k1; (void)k2; (void)nbuf;                                             \
    /* phase 1: m-half0 x all n. reads in consumption order (kk0 then kk1) */   \
    RD_A(0, 0, 0); RD_B(0, 0); RD_B(1, 0); RD_B(2, 0); RD_B(3, 0);              \
    RD_A(1, 0, 0); RD_A(2, 0, 0); RD_A(3, 0, 0);                                \
    RD_A(0, 0, 1); RD_B(0, 1); RD_B(1, 1); RD_B(2, 1); RD_B(3, 1);              \
    RD_A(1, 0, 1); RD_A(2, 0, 1); RD_A(3, 0, 1);                                \
    if (MODE <= 1) { STAGE_B(nbuf, 1, k1); STAGE_A(nbuf, 1, k1); }              \
    MFMA_H(0);                                                                  \
    BAR;                                                                        \
    /* phase 2: m-half1 (b frags reused from registers) */                      \
    RD_A(0, 1, 0); RD_A(1, 1, 0); RD_A(2, 1, 0); RD_A(3, 1, 0);                 \
    RD_A(0, 1, 1); RD_A(1, 1, 1); RD_A(2, 1, 1); RD_A(3, 1, 1);                 \
    if (MODE == 0) { STAGE_A(buf, 0, k2); STAGE_B(buf, 0, k2); VMC(4); }        \
    if (MODE == 1) { VMC(0); }                                                  \
    MFMA_H(1);                                                                  \
    BAR;                                                                        \
  }

  // Prologue: tile0 fully + A0/B0 of tile 1. Issue order matters for vmcnt:
  // [A0(0) B0(0) B1(0) A1(0)] then [A0(1) B0(1)] -> VMC(4) completes tile 0.
  STAGE_A(0, 0, 0); STAGE_B(0, 0, 0); STAGE_B(0, 1, 0); STAGE_A(0, 1, 0);
  STAGE_A(1, 0, 64); STAGE_B(1, 0, 64);
  VMC(4);
  BAR;

  const int NT = K >> 6;
  for (int t = 0; t < NT - 2; ++t) KTILE(t, 0);
  KTILE(NT - 2, 1);
  KTILE(NT - 1, 2);

#undef KTILE
#undef STAGE_A
#undef STAGE_B
#undef RD_A
#undef RD_B
#undef MFMA_H

  // Epilogue: silu(g)*u on interleaved even/odd columns, write H bf16.
  const int q4 = quad * 4;
#pragma unroll
  for (int mi = 0; mi < 8; ++mi) {
    const int row0 = m0 + (mi >> 2) * 128 + wm64 + (mi & 3) * 16 + q4;
#pragma unroll
    for (int ni = 0; ni < 4; ++ni) {
      const int col = n0 + (ni >> 1) * 128 + wn32 + (ni & 1) * 16 + l15;
#pragma unroll
      for (int rg = 0; rg < 4; ++rg) {
        const float v = acc[mi][ni][rg];
        const float p = __shfl_xor(v, 1);   // partner (g<->u)
        if ((l15 & 1) == 0) {
          const float hv = (v / (1.f + __expf(-v))) * p;  // silu(g)*u
          H[(size_t)(row0 + rg) * DI + (col >> 1)] = f2b(hv);
        }
      }
    }
  }
}

// ---------------- bf16 MFMA GEMM mainloop (128x128, BK=64) — GEMM2 ----------
__device__ __forceinline__ void gemm_mainloop(const short* __restrict__ A,
                                              const short* __restrict__ Bt,
                                              int K, int lda, int ldb,
                                              int m0, int n0,
                                              short* As, short* Bs,
                                              floatx4 (&acc)[4][4]) {
  const int wave = threadIdx.x >> 6;
  const int lane = threadIdx.x & 63;
  const int srow = lane >> 3;                   // row within 8-row staging chunk
  const int scol = ((lane & 7) ^ srow) * 8;     // swizzled source quarter (elems)
  const int wm = (wave & 1) * 64;
  const int wn = (wave >> 1) * 64;
  const int l15 = lane & 15;
  const int quad = lane >> 4;
  const int q0 = ((quad ^ (l15 & 7)) * 8);      // kk=0 read quarter offset (elems)

  for (int k0 = 0; k0 < K; k0 += 64) {
#pragma unroll
    for (int q = 0; q < 4; ++q) {
      const int chunk = wave * 4 + q;           // 16 chunks x 8 rows = 128 rows
      const int row = chunk * 8 + srow;
      gload_lds16(A + (size_t)(m0 + row) * lda + k0 + scol, &As[chunk * 8 * 64]);
      gload_lds16(Bt + (size_t)(n0 + row) * ldb + k0 + scol, &Bs[chunk * 8 * 64]);
    }
    __syncthreads();
#pragma unroll
    for (int kk = 0; kk < 2; ++kk) {
      const int qo = q0 ^ (kk * 32);            // (kk*4+quad)^(l15&7) in elems
      short8v af[4], bf[4];
#pragma unroll
      for (int i = 0; i < 4; ++i) {
        af[i] = *(const short8v*)&As[(wm + i * 16 + l15) * 64 + qo];
        bf[i] = *(const short8v*)&Bs[(wn + i * 16 + l15) * 64 + qo];
      }
#pragma unroll
      for (int mi = 0; mi < 4; ++mi)
#pragma unroll
        for (int ni = 0; ni < 4; ++ni)
          acc[mi][ni] = __builtin_amdgcn_mfma_f32_16x16x32_bf16(af[mi], bf[ni],
                                                                acc[mi][ni], 0, 0, 0);
    }
    __syncthreads();
  }
}

// GEMM2 with fused MoE epilogue.
__global__ __launch_bounds__(256) void gemm_bt_moe(const short* __restrict__ A,
                                                   const short* __restrict__ Bt,
                                                   float* __restrict__ out,
                                                   const float* __restrict__ x,
                                                   const float* __restrict__ cc,
                                                   const float* __restrict__ coef,
                                                   int K, int lda, int ldb) {
  __shared__ short As[128 * 64];
  __shared__ short Bs[128 * 64];
  floatx4 acc[4][4];
#pragma unroll
  for (int a = 0; a < 4; ++a)
#pragma unroll
    for (int b = 0; b < 4; ++b) acc[a][b] = (floatx4)0.0f;
  const int lin = blockIdx.y * gridDim.x + blockIdx.x;
  const int m0 = (lin & 31) * 128, n0 = (lin >> 5) * 128;
  gemm_mainloop(A, Bt, K, lda, ldb, m0, n0, As, Bs, acc);
  const int wave = threadIdx.x >> 6, lane = threadIdx.x & 63;
  const int wm = (wave & 1) * 64, wn = (wave >> 1) * 64;
  const int l15 = lane & 15, q4 = (lane >> 4) * 4;
#pragma unroll
  for (int mi = 0; mi < 4; ++mi) {
    const int row0 = m0 + wm + mi * 16 + q4;
#pragma unroll
    for (int ni = 0; ni < 4; ++ni) {
      const int col = n0 + wn + ni * 16 + l15;
      const float c0v = cc[col];
      const float c1v = cc[DH + col];
#pragma unroll
      for (int rg = 0; rg < 4; ++rg) {
        const int row = row0 + rg;
        const floatx4 cf = *(const floatx4*)&coef[row * 4];
        out[(size_t)row * DH + col] =
            cf[0] * x[(size_t)row * DH + col] + cf[1] * c0v + cf[2] * c1v +
            cf[3] * acc[mi][ni][rg];
      }
    }
  }
}

extern "C" void kernel_launch(void* const* d_in, const int* in_sizes, int n_in,
                              void* d_out, int out_size, void* d_ws, size_t ws_size,
                              hipStream_t stream) {
  const float* x   = (const float*)d_in[0];
  const float* gw1 = (const float*)d_in[1];
  const float* gw2 = (const float*)d_in[2];
  const float* cwg = (const float*)d_in[3];
  const float* cc  = (const float*)d_in[4];
  const float* wg  = (const float*)d_in[5];
  const float* wu  = (const float*)d_in[6];
  const float* wd  = (const float*)d_in[7];
  float* out = (float*)d_out;
  float* logits_out = out + (size_t)TOKS * DH;

  char* ws = (char*)d_ws;
  short* xb    = (short*)(ws);                          // 16.78 MB
  short* wgwuT = (short*)(ws + 16777216);               // [16384][2048] bf16 interleaved
  short* wdT   = (short*)(ws + 16777216 + 67108864);    // [2048][8192] bf16
  short* H     = (short*)(ws + 117440512);              // [4096][8192] bf16
  float* coef  = (float*)(ws + 117440512 + 67108864);   // [4096][4] fp32

  cvt_f32_to_bf16<<<(TOKS * DH) / (256 * 4), 256, 0, stream>>>(x, xb);
  transpose_to_bf16<<<dim3(DI / 32, DH / 32), 256, 0, stream>>>(wg, wgwuT, DH, DI, 2, 0);
  transpose_to_bf16<<<dim3(DI / 32, DH / 32), 256, 0, stream>>>(wu, wgwuT, DH, DI, 2, 1);
  transpose_to_bf16<<<dim3(DH / 32, DI / 32), 256, 0, stream>>>(wd, wdT, DI, DH, 1, 0);
  router_kernel<<<TOKS / RT_TPB, 256, 0, stream>>>(x, gw1, gw2, cwg, logits_out, coef);
  // 256x256 tiles: 16 m-tiles x 64 n-tiles = 1024 wgs, 512 threads
  gemm1_gu_silu<<<dim3((TOKS / 256) * ((2 * DI) / 256)), 512, 0, stream>>>(
      xb, wgwuT, H, DH, DH, DH);
  gemm_bt_moe<<<dim3(DH / 128, TOKS / 128), 256, 0, stream>>>(
      H, wdT, out, x, cc, coef, DI, DI, DI);
}